// Round 1
// baseline (977.694 us; speedup 1.0000x reference)
//
#include <hip/hip_runtime.h>

// Reference constants
constexpr int   TH    = 8;     // TREE_HEIGHT
constexpr int   NNEG  = 8;     // N_NEG
constexpr int   HID4  = 256;   // HIDDEN in float4 units (1024/4)
constexpr int   HALF4 = 128;   // SINGLE_DIM in float4 units (512/4)
constexpr float SCR_F = 6.2831853071795864769f; // 2*pi

// ---------------------------------------------------------------------------
// Kernel A: per-batch prep. Computes:
//   sp2[b][512]  = folded sum of the 8 p2 rows (low+high halves)
//   C[b][n]      = (diff_pos - 1 - (raw_n==0)) * 2pi   (algebraic collapse of
//                  all the diff/margin terms; emb[p1] cancels entirely)
// 2048 blocks x 128 threads. ~67 MB of reads, ~4.2 MB writes.
// ---------------------------------------------------------------------------
__global__ __launch_bounds__(128)
void prep_kernel(const float* __restrict__ emb,
                 const int*   __restrict__ pos_path,
                 const int*   __restrict__ neg_path,
                 float*       __restrict__ sp2_out,   // [BATCH][512]
                 float*       __restrict__ C_out)     // [BATCH][NNEG]
{
    const int b = blockIdx.x;
    const int t = threadIdx.x;          // 0..127

    __shared__ int s_p1[TH];
    __shared__ int s_p2[TH];

    if (t < TH) {
        s_p1[t] = pos_path[b * 2 * TH + t];
        s_p2[t] = pos_path[b * 2 * TH + TH + t];
    }
    __syncthreads();

    if (t < NNEG) {
        // intersection size p1 vs p2 (redundantly computed by 8 threads; cheap)
        int inter_pos = 0;
#pragma unroll
        for (int i = 0; i < TH; i++) {
            const int v = s_p1[i];
            bool f = false;
#pragma unroll
            for (int j = 0; j < TH; j++) f = f || (v == s_p2[j]);
            inter_pos += f ? 1 : 0;
        }
        const float diff_pos = fmaxf((float)(TH - inter_pos), 1.0f);

        // intersection size p1 vs neg[n]
        const int n = t;
        int negj[TH];
#pragma unroll
        for (int j = 0; j < TH; j++)
            negj[j] = neg_path[(b * NNEG + n) * TH + j];

        int inter_n = 0;
#pragma unroll
        for (int i = 0; i < TH; i++) {
            const int v = s_p1[i];
            bool f = false;
#pragma unroll
            for (int j = 0; j < TH; j++) f = f || (v == negj[j]);
            inter_n += f ? 1 : 0;
        }
        const int raw = TH - inter_n;   // diff_neg_raw (integer, >= 0)
        C_out[b * NNEG + n] = (diff_pos - 1.0f - (raw == 0 ? 1.0f : 0.0f)) * SCR_F;
    }

    // Folded sum of the 8 p2 rows
    const float4* __restrict__ embv = (const float4*)emb;
    float4 sp2 = {0.f, 0.f, 0.f, 0.f};
#pragma unroll
    for (int h = 0; h < TH; h++) {
        const float4* row = embv + (long)s_p2[h] * HID4;
        const float4 lo = row[t];
        const float4 hi = row[HALF4 + t];
        sp2.x += lo.x + hi.x;
        sp2.y += lo.y + hi.y;
        sp2.z += lo.z + hi.z;
        sp2.w += lo.w + hi.w;
    }
    ((float4*)sp2_out)[(long)b * HALF4 + t] = sp2;
}

// ---------------------------------------------------------------------------
// Kernel B: one block per (batch, neg) pair -> 16384 blocks x 128 threads.
// Each thread owns 4 columns of the folded 512-wide vector: gathers 8 rows
// (lo+hi), folds, applies C + 0.5*(sn - sp2), relu^2, block-reduces, sqrt,
// writes one partial. 8x the block count of the fused version -> full
// occupancy + deep dispatch queue for memory-level parallelism.
// Decode b = bn % BATCH: blocks sharing a batch land on the same XCD under
// round-robin dispatch (BATCH % 8 == 0), so sp2/C re-reads are L2-local.
// ---------------------------------------------------------------------------
__global__ __launch_bounds__(128)
void neg_kernel(const float* __restrict__ emb,
                const int*   __restrict__ neg_path,
                const float* __restrict__ sp2_in,    // [BATCH][512]
                const float* __restrict__ C_in,      // [BATCH][NNEG]
                float*       __restrict__ partial,   // [BATCH*NNEG]
                int batch)
{
    const int bn = blockIdx.x;
    const int b  = bn % batch;          // batch index (XCD-friendly decode)
    const int n  = bn / batch;          // neg index
    const int t  = threadIdx.x;         // 0..127
    const int idx = b * NNEG + n;

    // Block-uniform scalar loads (compiler emits s_load; no LDS needed)
    const int* __restrict__ neg = neg_path + (long)idx * TH;
    const float c = C_in[idx];

    const float4* __restrict__ embv = (const float4*)emb;
    float4 sn = {0.f, 0.f, 0.f, 0.f};
#pragma unroll
    for (int h = 0; h < TH; h++) {
        const float4* row = embv + (long)neg[h] * HID4;
        const float4 lo = row[t];
        const float4 hi = row[HALF4 + t];
        sn.x += lo.x + hi.x;
        sn.y += lo.y + hi.y;
        sn.z += lo.z + hi.z;
        sn.w += lo.w + hi.w;
    }

    const float4 sp2 = ((const float4*)sp2_in)[(long)b * HALF4 + t];
    float vx = c + 0.5f * (sn.x - sp2.x);
    float vy = c + 0.5f * (sn.y - sp2.y);
    float vz = c + 0.5f * (sn.z - sp2.z);
    float vw = c + 0.5f * (sn.w - sp2.w);
    vx = fmaxf(vx, 0.f); vy = fmaxf(vy, 0.f);
    vz = fmaxf(vz, 0.f); vw = fmaxf(vw, 0.f);
    float a = vx * vx + vy * vy + vz * vz + vw * vw;

    // Reduce 128 threads (2 waves)
#pragma unroll
    for (int off = 32; off > 0; off >>= 1) {
        a += __shfl_down(a, off, 64);
    }
    __shared__ float s_red[2];
    const int lane = t & 63;
    const int wid  = t >> 6;
    if (lane == 0) s_red[wid] = a;
    __syncthreads();
    if (t == 0) partial[idx] = sqrtf(s_red[0] + s_red[1]);
}

// ---------------------------------------------------------------------------
// Kernel C: single-block final reduction of the 16384 partials. Writes out[0]
// directly -> no zero-kernel, no atomics anywhere.
// ---------------------------------------------------------------------------
__global__ __launch_bounds__(256)
void reduce_kernel(const float* __restrict__ partial, int nval,
                   float* __restrict__ out)
{
    const int t = threadIdx.x;
    float s = 0.f;
    for (int i = t; i < nval; i += 256) s += partial[i];

#pragma unroll
    for (int off = 32; off > 0; off >>= 1) {
        s += __shfl_down(s, off, 64);
    }
    __shared__ float s_red[4];
    const int lane = t & 63;
    const int wid  = t >> 6;
    if (lane == 0) s_red[wid] = s;
    __syncthreads();
    if (t == 0) out[0] = s_red[0] + s_red[1] + s_red[2] + s_red[3];
}

extern "C" void kernel_launch(void* const* d_in, const int* in_sizes, int n_in,
                              void* d_out, int out_size, void* d_ws, size_t ws_size,
                              hipStream_t stream) {
    const float* emb      = (const float*)d_in[0];
    const int*   pos_path = (const int*)d_in[1];
    const int*   neg_path = (const int*)d_in[2];
    float*       out      = (float*)d_out;

    const int BATCH = in_sizes[1] / (2 * TH);   // 2048

    // Workspace layout (ws is >= 3 GB; we need ~4.3 MB)
    float* sp2     = (float*)d_ws;              // BATCH*512 floats
    float* Cb      = sp2 + (size_t)BATCH * 512; // BATCH*NNEG floats
    float* partial = Cb  + (size_t)BATCH * NNEG;// BATCH*NNEG floats

    prep_kernel<<<BATCH, 128, 0, stream>>>(emb, pos_path, neg_path, sp2, Cb);
    neg_kernel<<<BATCH * NNEG, 128, 0, stream>>>(emb, neg_path, sp2, Cb,
                                                 partial, BATCH);
    reduce_kernel<<<1, 256, 0, stream>>>(partial, BATCH * NNEG, out);
}

// Round 2
// 973.902 us; speedup vs baseline: 1.0039x; 1.0039x over previous
//
#include <hip/hip_runtime.h>

// Reference constants
constexpr int   TH    = 8;     // TREE_HEIGHT
constexpr int   NNEG  = 8;     // N_NEG
constexpr int   HID4  = 256;   // HIDDEN in float4 units (1024/4)
constexpr float SCR_F = 6.2831853071795864769f; // 2*pi

// ---------------------------------------------------------------------------
// Kernel A: per-batch prep, ONE WAVE per batch element (64 threads, no LDS,
// no syncthreads). Lane l owns folded float4-columns {l, 64+l}.
//   sp2[b][512] = folded sum of the 8 p2 rows    (32 independent 1KB loads)
//   C[b][n]     = (diff_pos - 1 - (raw_n==0)) * 2pi
// ---------------------------------------------------------------------------
__global__ __launch_bounds__(64, 2)
void prep_kernel(const float* __restrict__ emb,
                 const int*   __restrict__ pos_path,
                 const int*   __restrict__ neg_path,
                 float*       __restrict__ sp2_out,   // [BATCH][512]
                 float*       __restrict__ C_out)     // [BATCH][NNEG]
{
    const int b = blockIdx.x;
    const int l = threadIdx.x;          // 0..63

    // --- scalar work: C[b][n] on lanes 0..7 (redundant loads, cached) ---
    if (l < NNEG) {
        int p1v[TH], p2v[TH];
#pragma unroll
        for (int i = 0; i < TH; i++) {
            p1v[i] = pos_path[b * 2 * TH + i];
            p2v[i] = pos_path[b * 2 * TH + TH + i];
        }
        int inter_pos = 0;
#pragma unroll
        for (int i = 0; i < TH; i++) {
            bool f = false;
#pragma unroll
            for (int j = 0; j < TH; j++) f = f || (p1v[i] == p2v[j]);
            inter_pos += f ? 1 : 0;
        }
        const float diff_pos = fmaxf((float)(TH - inter_pos), 1.0f);

        const int n = l;
        int negj[TH];
#pragma unroll
        for (int j = 0; j < TH; j++)
            negj[j] = neg_path[(b * NNEG + n) * TH + j];

        int inter_n = 0;
#pragma unroll
        for (int i = 0; i < TH; i++) {
            bool f = false;
#pragma unroll
            for (int j = 0; j < TH; j++) f = f || (p1v[i] == negj[j]);
            inter_n += f ? 1 : 0;
        }
        const int raw = TH - inter_n;   // diff_neg_raw (integer, >= 0)
        C_out[b * NNEG + n] = (diff_pos - 1.0f - (raw == 0 ? 1.0f : 0.0f)) * SCR_F;
    }

    // --- folded sum of the 8 p2 rows: 32 independent 1KB wave-loads ---
    const float4* __restrict__ embv = (const float4*)emb;
    float4 s0 = {0.f, 0.f, 0.f, 0.f};   // folded cols [4l .. 4l+3]
    float4 s1 = {0.f, 0.f, 0.f, 0.f};   // folded cols [256+4l .. 256+4l+3]
#pragma unroll
    for (int h = 0; h < TH; h++) {
        const int r = pos_path[b * 2 * TH + TH + h];   // p2[h], wave-uniform
        const float4* row = embv + (long)r * HID4;
        const float4 a0 = row[l];           // floats [4l   .. ]
        const float4 a1 = row[64 + l];      // floats [256+4l ..]
        const float4 a2 = row[128 + l];     // floats [512+4l ..]  (high half)
        const float4 a3 = row[192 + l];     // floats [768+4l ..]
        s0.x += a0.x + a2.x; s0.y += a0.y + a2.y;
        s0.z += a0.z + a2.z; s0.w += a0.w + a2.w;
        s1.x += a1.x + a3.x; s1.y += a1.y + a3.y;
        s1.z += a1.z + a3.z; s1.w += a1.w + a3.w;
    }
    float4* sp2v = (float4*)sp2_out;
    sp2v[(long)b * 128 + l]      = s0;
    sp2v[(long)b * 128 + 64 + l] = s1;
}

// ---------------------------------------------------------------------------
// Kernel B: ONE WAVE per (batch, neg) pair -> 16384 blocks x 64 threads.
// Lane l owns folded float4-columns {l, 64+l}. The 8-row gather issues
// 32 independent 1KB loads (32KB in flight per wave), no LDS, no barriers;
// the reduction is a pure in-wave butterfly. __launch_bounds__(64,2) gives
// the compiler 256 VGPRs so all 32 loads can stay in flight.
// ---------------------------------------------------------------------------
__global__ __launch_bounds__(64, 2)
void neg_kernel(const float* __restrict__ emb,
                const int*   __restrict__ neg_path,
                const float* __restrict__ sp2_in,    // [BATCH][512]
                const float* __restrict__ C_in,      // [BATCH][NNEG]
                float*       __restrict__ partial,   // [BATCH*NNEG]
                int batch)
{
    const int bn = blockIdx.x;
    const int b  = bn % batch;          // batch index
    const int n  = bn / batch;          // neg index
    const int l  = threadIdx.x;         // 0..63
    const int idx = b * NNEG + n;

    // Wave-uniform index loads (scalarized by compiler)
    const int4* __restrict__ npv = (const int4*)(neg_path + (long)idx * TH);
    const int4 nlo = npv[0];
    const int4 nhi = npv[1];
    const int ridx[TH] = {nlo.x, nlo.y, nlo.z, nlo.w, nhi.x, nhi.y, nhi.z, nhi.w};
    const float c = C_in[idx];

    const float4* __restrict__ embv = (const float4*)emb;
    float4 s0 = {0.f, 0.f, 0.f, 0.f};
    float4 s1 = {0.f, 0.f, 0.f, 0.f};
#pragma unroll
    for (int h = 0; h < TH; h++) {
        const float4* row = embv + (long)ridx[h] * HID4;
        const float4 a0 = row[l];
        const float4 a1 = row[64 + l];
        const float4 a2 = row[128 + l];
        const float4 a3 = row[192 + l];
        s0.x += a0.x + a2.x; s0.y += a0.y + a2.y;
        s0.z += a0.z + a2.z; s0.w += a0.w + a2.w;
        s1.x += a1.x + a3.x; s1.y += a1.y + a3.y;
        s1.z += a1.z + a3.z; s1.w += a1.w + a3.w;
    }

    const float4* sp2v = (const float4*)sp2_in;
    const float4 p0 = sp2v[(long)b * 128 + l];
    const float4 p1 = sp2v[(long)b * 128 + 64 + l];

    float v, a = 0.f;
    v = c + 0.5f * (s0.x - p0.x); v = fmaxf(v, 0.f); a += v * v;
    v = c + 0.5f * (s0.y - p0.y); v = fmaxf(v, 0.f); a += v * v;
    v = c + 0.5f * (s0.z - p0.z); v = fmaxf(v, 0.f); a += v * v;
    v = c + 0.5f * (s0.w - p0.w); v = fmaxf(v, 0.f); a += v * v;
    v = c + 0.5f * (s1.x - p1.x); v = fmaxf(v, 0.f); a += v * v;
    v = c + 0.5f * (s1.y - p1.y); v = fmaxf(v, 0.f); a += v * v;
    v = c + 0.5f * (s1.z - p1.z); v = fmaxf(v, 0.f); a += v * v;
    v = c + 0.5f * (s1.w - p1.w); v = fmaxf(v, 0.f); a += v * v;

    // In-wave butterfly reduce (no LDS, no barrier)
#pragma unroll
    for (int off = 32; off > 0; off >>= 1) {
        a += __shfl_down(a, off, 64);
    }
    if (l == 0) partial[idx] = sqrtf(a);
}

// ---------------------------------------------------------------------------
// Kernel C: single-block final reduction of the 16384 partials -> out[0].
// ---------------------------------------------------------------------------
__global__ __launch_bounds__(1024)
void reduce_kernel(const float* __restrict__ partial, int nval,
                   float* __restrict__ out)
{
    const int t = threadIdx.x;
    float s = 0.f;
    for (int i = t; i < nval; i += 1024) s += partial[i];

#pragma unroll
    for (int off = 32; off > 0; off >>= 1) {
        s += __shfl_down(s, off, 64);
    }
    __shared__ float s_red[16];
    const int lane = t & 63;
    const int wid  = t >> 6;
    if (lane == 0) s_red[wid] = s;
    __syncthreads();
    if (t == 0) {
        float tot = 0.f;
#pragma unroll
        for (int w = 0; w < 16; w++) tot += s_red[w];
        out[0] = tot;
    }
}

extern "C" void kernel_launch(void* const* d_in, const int* in_sizes, int n_in,
                              void* d_out, int out_size, void* d_ws, size_t ws_size,
                              hipStream_t stream) {
    const float* emb      = (const float*)d_in[0];
    const int*   pos_path = (const int*)d_in[1];
    const int*   neg_path = (const int*)d_in[2];
    float*       out      = (float*)d_out;

    const int BATCH = in_sizes[1] / (2 * TH);   // 2048

    // Workspace layout (ws is >= 3 GB; we need ~4.3 MB)
    float* sp2     = (float*)d_ws;              // BATCH*512 floats
    float* Cb      = sp2 + (size_t)BATCH * 512; // BATCH*NNEG floats
    float* partial = Cb  + (size_t)BATCH * NNEG;// BATCH*NNEG floats

    prep_kernel<<<BATCH, 64, 0, stream>>>(emb, pos_path, neg_path, sp2, Cb);
    neg_kernel<<<BATCH * NNEG, 64, 0, stream>>>(emb, neg_path, sp2, Cb,
                                                partial, BATCH);
    reduce_kernel<<<1, 1024, 0, stream>>>(partial, BATCH * NNEG, out);
}